// Round 8
// baseline (978.163 us; speedup 1.0000x reference)
//
#include <hip/hip_runtime.h>
#include <hip/hip_bf16.h>
#include <stdint.h>

// ---------------------------------------------------------------------------
// HConstructor: slot-attention-like block on MI355X.
//   inputs [65536,256], noise [1024,256] -> edges [1024,256], H [65536,1024],
//   dots2 [65536,1024].
// Pipeline (all on `stream`):
//   prep_w   : Wcat^T = [wk|wv|wq]^T as bf16 [768,256], bias cat
//   edges_e  : edges = mu + exp(ls)*noise ; e = LN(edges)  (f32 + bf16)
//   ln_x     : x = LN(inputs) -> bf16 [65536,256]
//   gemm<1>  : q  = relu(e @ wq + bq)           [1024,256]  bf16
//   gemm<0>  : k,v = relu(x@wk/v + b) -> H-region; q2 strided into dots2 rows
//   gemm<2>  : dots = (q @ k^T) * 1/16 -> bf16 [1024,65536] (H-region scratch)
//   d2d3     : per row: 2-level lane-indexed histogram rank-select + sparse
//              attn@v gather (R6 version, ~161us).
//   mlp      : edges_out = relu([e,upd]@w1+b1)@w2+b2 -> OUT + bf16
//   gemm<1>  : k2 = relu(edges_out @ wk + bk) -> d_ws (512 KB)
//   d3h v2   : FUSED dots2 + H with the 32x1024 f32 tile in LDS (128 KB) --
//              R7's global round-trip missed L2 (FETCH 258 MB, k2 streaming
//              evicted the slice) and scalar stores inflated WRITE to 743 MB.
//              Now: MFMA -> LDS tile -> one barrier -> per-wave softmax/top-ke
//              from LDS -> float4 streaming writes of dots2 AND H.  Zero
//              global readback.
// Scratch map:
//   H region   : dots(134M) | xln(32M) | kb(32M) | vb(32M) | smalls(~4M)
//   dots2 reg. : q2-strided tiles (consumed block-locally by d3h)
//   d_ws       : k2 bf16 (512 KB)
// ---------------------------------------------------------------------------

#define DEV __device__ __forceinline__

typedef uint32_t u32;
typedef uint16_t u16;
typedef __bf16 v8bf __attribute__((ext_vector_type(8)));
typedef float v4f __attribute__((ext_vector_type(4)));

static constexpr long NN = 65536;
static constexpr long DD = 256;
static constexpr long NSL = 1024;

DEV u16 f2b(float f) {
  u32 u = __builtin_bit_cast(u32, f);
  u32 r = (u + 0x7FFFu + ((u >> 16) & 1u)) >> 16;
  return (u16)r;
}
DEV float b2f(u16 h) { u32 u = ((u32)h) << 16; return __builtin_bit_cast(float, u); }
// bf16 bits (as u32 low16) -> monotone sortable 16-bit key
DEV u32 b2k(u32 b) { return b ^ (0x8000u + 0x7FFFu * (b >> 15)); }
DEV float k2fv(u32 k) {
  u16 b = (k & 0x8000u) ? (u16)(k ^ 0x8000u) : (u16)(k ^ 0xFFFFu);
  return b2f(b);
}

// ---------------------------------------------------------------------------
// Generic  C[M,N] = epilogue(A[M,256] @ B[N,256]^T)   (bf16 in, MFMA 16x16x32)
// 128x128 tile, BK=64, 4 waves (2x2), XOR-swizzled LDS (16B chunk ^ row&7).
// EPI 0: +biascat, relu for cols<512, route {0:k,1:v,2:q2-strided} bf16
// EPI 1: +bias, relu, bf16 out [M,256]
// EPI 2: *scale, bf16 out ld=65536
// ---------------------------------------------------------------------------
template <int EPI>
__global__ __launch_bounds__(256, 2)
void gemm_bt(const u16* __restrict__ A, const u16* __restrict__ B,
             const float* __restrict__ bias, float scale,
             u16* __restrict__ ob0, u16* __restrict__ ob1, u16* __restrict__ ob2,
             float* __restrict__ of) {
  __shared__ __align__(16) u16 As[128 * 64];
  __shared__ __align__(16) u16 Bs[128 * 64];
  const int tid = threadIdx.x;
  const int lane = tid & 63;
  const int l15 = lane & 15;
  const int l4 = lane >> 4;
  const int wid = tid >> 6;
  const int wm = wid >> 1, wn = wid & 1;
  const long m0 = (long)blockIdx.y * 128;
  const long n0 = (long)blockIdx.x * 128;

  v4f acc[4][4] = {};

  for (int kb = 0; kb < 256; kb += 64) {
    __syncthreads();
#pragma unroll
    for (int i = 0; i < 4; i++) {
      int cid = tid + 256 * i;          // 1024 16B-chunks per tile
      int row = cid >> 3, ch = cid & 7; // 8 chunks per 64-col row
      int sch = ch ^ (row & 7);
      uint4 da = *reinterpret_cast<const uint4*>(A + (m0 + row) * 256 + kb + ch * 8);
      *reinterpret_cast<uint4*>(&As[row * 64 + sch * 8]) = da;
      uint4 db = *reinterpret_cast<const uint4*>(B + (n0 + row) * 256 + kb + ch * 8);
      *reinterpret_cast<uint4*>(&Bs[row * 64 + sch * 8]) = db;
    }
    __syncthreads();
#pragma unroll
    for (int ks = 0; ks < 2; ks++) {
      v8bf af[4], bfr[4];
#pragma unroll
      for (int m = 0; m < 4; m++) {
        int row = wm * 64 + m * 16 + l15;
        int sch = (ks * 4 + l4) ^ (row & 7);
        af[m] = *reinterpret_cast<const v8bf*>(&As[row * 64 + sch * 8]);
      }
#pragma unroll
      for (int n = 0; n < 4; n++) {
        int row = wn * 64 + n * 16 + l15;
        int sch = (ks * 4 + l4) ^ (row & 7);
        bfr[n] = *reinterpret_cast<const v8bf*>(&Bs[row * 64 + sch * 8]);
      }
#pragma unroll
      for (int m = 0; m < 4; m++)
#pragma unroll
        for (int n = 0; n < 4; n++)
          acc[m][n] = __builtin_amdgcn_mfma_f32_16x16x32_bf16(af[m], bfr[n], acc[m][n], 0, 0, 0);
    }
  }

  const int r4 = l4 * 4;
#pragma unroll
  for (int m = 0; m < 4; m++) {
#pragma unroll
    for (int n = 0; n < 4; n++) {
#pragma unroll
      for (int r = 0; r < 4; r++) {
        long grow = m0 + wm * 64 + m * 16 + r4 + r;
        long gcol = n0 + wn * 64 + n * 16 + l15;
        float v = acc[m][n][r];
        if constexpr (EPI == 0) {
          v += bias[gcol];
          int which = (int)(gcol >> 8);
          long jj = gcol & 255;
          if (which < 2) v = fmaxf(v, 0.f);
          u16 hv = f2b(v);
          if (which == 0) ob0[grow * 256 + jj] = hv;
          else if (which == 1) ob1[grow * 256 + jj] = hv;
          else ob2[(grow & ~31L) * 2048 + (grow & 31) * 256 + jj] = hv;  // q2 strided
        } else if constexpr (EPI == 1) {
          v += bias[gcol];
          v = fmaxf(v, 0.f);
          ob0[grow * 256 + gcol] = f2b(v);
        } else if constexpr (EPI == 2) {
          ob0[grow * 65536 + gcol] = f2b(v * scale);
        } else {
          of[grow * 1024 + gcol] = v * scale;
        }
      }
    }
  }
}

// ---------------------------------------------------------------------------
// Weight prep: Wcat^T bf16 [768,256] rows = [wk cols | wv cols | wq cols]
// ---------------------------------------------------------------------------
__global__ __launch_bounds__(256)
void prep_w_kernel(const float* __restrict__ wq, const float* __restrict__ wk,
                   const float* __restrict__ wv, const float* __restrict__ bq,
                   const float* __restrict__ bk, const float* __restrict__ bv,
                   u16* __restrict__ wcat, float* __restrict__ bcat) {
  int n = blockIdx.x;
  int t = threadIdx.x;
  const float* W = (n < 256) ? wk : (n < 512) ? wv : wq;
  int jj = n & 255;
  wcat[n * 256 + t] = f2b(W[t * 256 + jj]);
  if (t == 0) {
    const float* Bb = (n < 256) ? bk : (n < 512) ? bv : bq;
    bcat[n] = Bb[jj];
  }
}

// ---------------------------------------------------------------------------
// x = LayerNorm(inputs) -> bf16.  One wave per row (4 f32 per lane).
// ---------------------------------------------------------------------------
__global__ __launch_bounds__(256)
void ln_x_kernel(const float* __restrict__ x, const float* __restrict__ lw,
                 const float* __restrict__ lb, u16* __restrict__ out) {
  const int lane = threadIdx.x & 63, wid = threadIdx.x >> 6;
  const long row = (long)blockIdx.x * 4 + wid;
  float4 v = reinterpret_cast<const float4*>(x + row * 256)[lane];
  float s = v.x + v.y + v.z + v.w;
  for (int sh = 1; sh < 64; sh <<= 1) s += __shfl_xor(s, sh);
  float mu = s * (1.f / 256.f);
  float dx = v.x - mu, dy = v.y - mu, dz = v.z - mu, dw = v.w - mu;
  float q = dx * dx + dy * dy + dz * dz + dw * dw;
  for (int sh = 1; sh < 64; sh <<= 1) q += __shfl_xor(q, sh);
  float rs = rsqrtf(q * (1.f / 256.f) + 1e-5f);
  float4 wv = reinterpret_cast<const float4*>(lw)[lane];
  float4 bv = reinterpret_cast<const float4*>(lb)[lane];
  ushort4 o4;
  o4.x = f2b(dx * rs * wv.x + bv.x);
  o4.y = f2b(dy * rs * wv.y + bv.y);
  o4.z = f2b(dz * rs * wv.z + bv.z);
  o4.w = f2b(dw * rs * wv.w + bv.w);
  reinterpret_cast<ushort4*>(out + row * 256)[lane] = o4;
}

// ---------------------------------------------------------------------------
// edges = mu + exp(ls)*noise ; e = LayerNorm(edges) -> f32 + bf16
// ---------------------------------------------------------------------------
__global__ __launch_bounds__(256)
void edges_e_kernel(const float* __restrict__ noise, const float* __restrict__ emu,
                    const float* __restrict__ els, const float* __restrict__ lw,
                    const float* __restrict__ lb, float* __restrict__ e_f,
                    u16* __restrict__ e_b) {
  const int lane = threadIdx.x & 63, wid = threadIdx.x >> 6;
  const long row = (long)blockIdx.x * 4 + wid;
  float4 nz = reinterpret_cast<const float4*>(noise + row * 256)[lane];
  float4 mu4 = reinterpret_cast<const float4*>(emu)[lane];
  float4 ls4 = reinterpret_cast<const float4*>(els)[lane];
  float4 ed;
  ed.x = mu4.x + expf(ls4.x) * nz.x;
  ed.y = mu4.y + expf(ls4.y) * nz.y;
  ed.z = mu4.z + expf(ls4.z) * nz.z;
  ed.w = mu4.w + expf(ls4.w) * nz.w;
  float s = ed.x + ed.y + ed.z + ed.w;
  for (int sh = 1; sh < 64; sh <<= 1) s += __shfl_xor(s, sh);
  float mu = s * (1.f / 256.f);
  float dx = ed.x - mu, dy = ed.y - mu, dz = ed.z - mu, dw = ed.w - mu;
  float qv = dx * dx + dy * dy + dz * dz + dw * dw;
  for (int sh = 1; sh < 64; sh <<= 1) qv += __shfl_xor(qv, sh);
  float rs = rsqrtf(qv * (1.f / 256.f) + 1e-5f);
  float4 wv = reinterpret_cast<const float4*>(lw)[lane];
  float4 bv = reinterpret_cast<const float4*>(lb)[lane];
  float4 ef;
  ef.x = dx * rs * wv.x + bv.x;
  ef.y = dy * rs * wv.y + bv.y;
  ef.z = dz * rs * wv.z + bv.z;
  ef.w = dw * rs * wv.w + bv.w;
  reinterpret_cast<float4*>(e_f + row * 256)[lane] = ef;
  ushort4 o4;
  o4.x = f2b(ef.x); o4.y = f2b(ef.y); o4.z = f2b(ef.z); o4.w = f2b(ef.w);
  reinterpret_cast<ushort4*>(e_b + row * 256)[lane] = o4;
}

// ---------------------------------------------------------------------------
// d2d3 (unchanged from R6): 2-level lane-indexed histogram rank select +
// sparse attn@v gather.  Fixed softmax shift C=8 (dots >= 0, O(5)).
// ---------------------------------------------------------------------------
struct D3Shm {
  uint4 SK4[8192];        // 128 KiB packed keys (2 x u16 per u32)
  u32 hist[256 * 16];     // 16 KiB: bin b, copy c at [b*16+c]
  u32 c_hi[256];
  u32 sel_idx[1152];
  float sel_w[1152];
  float fred[16];
  u32 sb_star, sThi, sThr;
  float sSE, sFrac;
  u32 scnt;
};

__global__ __launch_bounds__(1024, 4)
void d2d3_kernel(const u16* __restrict__ dots, const u16* __restrict__ vmat,
                 const int* __restrict__ knp, float* __restrict__ upd) {
  extern __shared__ char d3smem[];
  D3Shm* S = reinterpret_cast<D3Shm*>(d3smem);
  const int tid = threadIdx.x, lane = tid & 63, wid = tid >> 6;
  const int hc = (lane >> 2);          // 16 lane-indexed histogram copies
  const long r = blockIdx.x;
  const int kn = *knp;

  for (int i = tid; i < 4096; i += 1024) S->hist[i] = 0;
  if (tid == 0) S->scnt = 0;
  __syncthreads();

  const float C = 8.f;
  const uint4* src = reinterpret_cast<const uint4*>(dots + r * 65536);

  float se = 0.f;
#pragma unroll
  for (int q = 0; q < 8; q++) {
    uint4 d = src[tid + 1024 * q];
    u32 h[8] = {d.x & 0xffffu, d.x >> 16, d.y & 0xffffu, d.y >> 16,
                d.z & 0xffffu, d.z >> 16, d.w & 0xffffu, d.w >> 16};
    u32 k[8];
#pragma unroll
    for (int j = 0; j < 8; j++) {
      k[j] = b2k(h[j]);
      se += __expf(b2f((u16)h[j]) - C);
      atomicAdd(&S->hist[(k[j] >> 8) * 16 + hc], 1u);
    }
    uint4 kq;
    kq.x = k[0] | (k[1] << 16); kq.y = k[2] | (k[3] << 16);
    kq.z = k[4] | (k[5] << 16); kq.w = k[6] | (k[7] << 16);
    S->SK4[q * 1024 + tid] = kq;
  }
  for (int sh = 1; sh < 64; sh <<= 1) se += __shfl_xor(se, sh);
  if (lane == 0) S->fred[wid] = se;
  __syncthreads();

  if (tid < 256) {
    u32 s = 0;
#pragma unroll
    for (int c = 0; c < 16; c++) s += S->hist[tid * 16 + c];
    S->c_hi[tid] = s;
  }
  __syncthreads();

  if (tid < 64) {
    u32 s = S->c_hi[4 * tid] + S->c_hi[4 * tid + 1] + S->c_hi[4 * tid + 2] + S->c_hi[4 * tid + 3];
    u32 v = s;
    for (int off = 1; off < 64; off <<= 1) {
      u32 t = (u32)__shfl_down((int)v, off);
      if (tid + off < 64) v += t;
    }
    u32 excl = v - s;
    if (v >= (u32)kn && excl < (u32)kn) {
      u32 acc = excl;
#pragma unroll
      for (int bb = 3; bb >= 0; --bb) {
        int b = 4 * tid + bb;
        u32 nb = acc + S->c_hi[b];
        if (nb >= (u32)kn) { S->sb_star = (u32)b; S->sThi = acc; break; }
        acc = nb;
      }
    }
  } else {
    for (int i = tid - 64; i < 4096; i += 960) S->hist[i] = 0;
  }
  __syncthreads();
  const u32 bstar = S->sb_star;

#pragma unroll
  for (int q = 0; q < 8; q++) {
    uint4 kq = S->SK4[q * 1024 + tid];
    u32 w[4] = {kq.x, kq.y, kq.z, kq.w};
#pragma unroll
    for (int j = 0; j < 4; j++) {
      u32 kl = w[j] & 0xffffu, kh = w[j] >> 16;
      if ((kl >> 8) == bstar) atomicAdd(&S->hist[(kl & 255u) * 16 + hc], 1u);
      if ((kh >> 8) == bstar) atomicAdd(&S->hist[(kh & 255u) * 16 + hc], 1u);
    }
  }
  __syncthreads();
  if (tid < 256) {
    u32 s = 0;
#pragma unroll
    for (int c = 0; c < 16; c++) s += S->hist[tid * 16 + c];
    S->c_hi[tid] = s;
  }
  __syncthreads();

  if (tid < 64) {
    u32 s = S->c_hi[4 * tid] + S->c_hi[4 * tid + 1] + S->c_hi[4 * tid + 2] + S->c_hi[4 * tid + 3];
    u32 v = s;
    for (int off = 1; off < 64; off <<= 1) {
      u32 t = (u32)__shfl_down((int)v, off);
      if (tid + off < 64) v += t;
    }
    const u32 Thi = S->sThi;
    u32 incl = v + Thi;
    u32 excl = v - s + Thi;
    if (incl >= (u32)kn && excl < (u32)kn) {
      u32 acc = excl;
#pragma unroll
      for (int bb = 3; bb >= 0; --bb) {
        int b = 4 * tid + bb;
        u32 nb = acc + S->c_hi[b];
        if (nb >= (u32)kn) {
          S->sThr = (bstar << 8) | (u32)b;
          S->sFrac = (float)(int)((u32)kn - acc) / (float)S->c_hi[b];
          break;
        }
        acc = nb;
      }
    }
    if (tid == 0) {
      float SE = 0.f;
#pragma unroll
      for (int i = 0; i < 16; i++) SE += S->fred[i];
      S->sSE = SE;
    }
  }
  __syncthreads();
  const u32 thr = S->sThr;
  const float frac = S->sFrac;
  const float invs = 1.f / S->sSE;
  const float wnorm = 1.f / (1.f + 65536.f * 1e-8f);

#pragma unroll
  for (int q = 0; q < 8; q++) {
    uint4 kq = S->SK4[q * 1024 + tid];
    const u32 base = (u32)(tid + 1024 * q) * 8;
    u32 kk[8] = {kq.x & 0xffffu, kq.x >> 16, kq.y & 0xffffu, kq.y >> 16,
                 kq.z & 0xffffu, kq.z >> 16, kq.w & 0xffffu, kq.w >> 16};
#pragma unroll
    for (int j = 0; j < 8; j++) {
      if (kk[j] >= thr) {
        float w = (__expf(k2fv(kk[j]) - C) * invs + 1e-8f) * wnorm;
        if (kk[j] == thr) w *= frac;
        u32 p = atomicAdd(&S->scnt, 1u);
        if (p < 1152u) { S->sel_idx[p] = base + (u32)j; S->sel_w[p] = w; }
      }
    }
  }
  __syncthreads();
  const u32 nsel = S->scnt < 1152u ? S->scnt : 1152u;

  float* partial = reinterpret_cast<float*>(S->SK4);
  const int g = tid >> 8, col = tid & 255;
  float a0 = 0.f, a1 = 0.f, a2 = 0.f, a3 = 0.f;
  u32 j = (u32)g;
  for (; j + 12 < nsel; j += 16) {
    a0 = fmaf(S->sel_w[j], b2f(vmat[(long)S->sel_idx[j] * 256 + col]), a0);
    a1 = fmaf(S->sel_w[j + 4], b2f(vmat[(long)S->sel_idx[j + 4] * 256 + col]), a1);
    a2 = fmaf(S->sel_w[j + 8], b2f(vmat[(long)S->sel_idx[j + 8] * 256 + col]), a2);
    a3 = fmaf(S->sel_w[j + 12], b2f(vmat[(long)S->sel_idx[j + 12] * 256 + col]), a3);
  }
  for (; j < nsel; j += 4)
    a0 = fmaf(S->sel_w[j], b2f(vmat[(long)S->sel_idx[j] * 256 + col]), a0);
  partial[tid] = (a0 + a1) + (a2 + a3);
  __syncthreads();
  if (tid < 256)
    upd[r * 256 + tid] = partial[tid] + partial[256 + tid] + partial[512 + tid] + partial[768 + tid];
}

// ---------------------------------------------------------------------------
// mlp: edges_out = relu([e, upd] @ w1 + b1) @ w2 + b2   (f32, one block/row)
// ---------------------------------------------------------------------------
__global__ __launch_bounds__(256)
void mlp_kernel(const float* __restrict__ e, const float* __restrict__ upd,
                const float* __restrict__ w1, const float* __restrict__ b1,
                const float* __restrict__ w2, const float* __restrict__ b2,
                float* __restrict__ eout, u16* __restrict__ eb) {
  __shared__ float ecat[512];
  __shared__ float h[256];
  const int t = threadIdx.x;
  const long r = blockIdx.x;
  ecat[t] = e[r * 256 + t];
  ecat[256 + t] = upd[r * 256 + t];
  __syncthreads();
  float acc = b1[t];
#pragma unroll 8
  for (int kk = 0; kk < 512; ++kk) acc = fmaf(ecat[kk], w1[kk * 256 + t], acc);
  h[t] = fmaxf(acc, 0.f);
  __syncthreads();
  float a2 = b2[t];
#pragma unroll 8
  for (int kk = 0; kk < 256; ++kk) a2 = fmaf(h[kk], w2[kk * 256 + t], a2);
  eout[r * 256 + t] = a2;
  eb[r * 256 + t] = f2b(a2);
}

// ---------------------------------------------------------------------------
// d3h v2: FUSED dots2 + H, tile resident in LDS.  One block = 32 rows.
// 512 threads, 8 waves as 2(M: 16 rows) x 4(N: 16 cols per 64-col chunk).
//   phase 1: stage own q2 tile [32][256] swizzled (16 KB)
//   phase 2: 16 nc-chunks x 4 kb: stage k2 [64][64] (8 KB), MFMA; after each
//            nc, dump acc into the LDS f32 tile (128 KB)
//   phase 3: one barrier; per wave: 4 rows -> softmax + top-ke search from
//            LDS; float4 streaming writes of dots2 and H (no readback).
// LDS total 152 KB -> 1 block/CU.
// ---------------------------------------------------------------------------
struct D3HShm {
  float tile[32 * 1024];   // 128 KiB
  u16 Aq[32 * 256];        // 16 KiB
  u16 Bk[64 * 64];         // 8 KiB
};

__global__ __launch_bounds__(512, 2)
void d3h_kernel(const u16* __restrict__ q2s, const u16* __restrict__ k2,
                const int* __restrict__ kep, float* __restrict__ d2out,
                float* __restrict__ H) {
  extern __shared__ char d3hsm[];
  D3HShm* S = reinterpret_cast<D3HShm*>(d3hsm);
  const int tid = threadIdx.x;
  const int lane = tid & 63;
  const int l15 = lane & 15;
  const int l4 = lane >> 4;
  const int w = tid >> 6;
  const int wm = w >> 2, wn = w & 3;
  const long m0 = (long)blockIdx.x * 32;

  // ---- phase 1: stage q2 tile [32][256] as 4 sub-tiles [32][64] swizzled ----
  const u16* q2blk = q2s + m0 * 2048;          // own strided slot
#pragma unroll
  for (int i = 0; i < 2; i++) {
    int cid = tid + 512 * i;                   // 1024 16B chunks
    int row = cid >> 5, ch32 = cid & 31;
    int kb = ch32 >> 3, ch = ch32 & 7;
    int sch = ch ^ (row & 7);
    uint4 d = *reinterpret_cast<const uint4*>(q2blk + row * 256 + ch32 * 8);
    *reinterpret_cast<uint4*>(&S->Aq[kb * 2048 + row * 64 + sch * 8]) = d;
  }

  const int arow = wm * 16 + l15;
  const int brow = wn * 16 + l15;

  // ---- phase 2: 16 col-chunks of 64; accumulate, dump into LDS tile ----
#pragma unroll
  for (int nc = 0; nc < 16; nc++) {
    v4f acc = {};
#pragma unroll
    for (int kb = 0; kb < 4; kb++) {
      __syncthreads();
      {
        int row = tid >> 3, ch = tid & 7;      // 512 16B chunks
        int sch = ch ^ (row & 7);
        uint4 d = *reinterpret_cast<const uint4*>(k2 + (nc * 64 + row) * 256 + kb * 64 + ch * 8);
        *reinterpret_cast<uint4*>(&S->Bk[row * 64 + sch * 8]) = d;
      }
      __syncthreads();
#pragma unroll
      for (int ks = 0; ks < 2; ks++) {
        v8bf a = *reinterpret_cast<const v8bf*>(
            &S->Aq[kb * 2048 + arow * 64 + (((ks * 4 + l4) ^ (arow & 7))) * 8]);
        v8bf b = *reinterpret_cast<const v8bf*>(
            &S->Bk[brow * 64 + (((ks * 4 + l4) ^ (brow & 7))) * 8]);
        acc = __builtin_amdgcn_mfma_f32_16x16x32_bf16(a, b, acc, 0, 0, 0);
      }
    }
    // dump: C layout col=lane&15, row=(lane>>4)*4+r
#pragma unroll
    for (int r = 0; r < 4; r++)
      S->tile[(wm * 16 + l4 * 4 + r) * 1024 + nc * 64 + wn * 16 + l15] = acc[r] * 0.0625f;
  }
  __syncthreads();

  // ---- phase 3: per-wave g2 on 4 rows from LDS; stream dots2 + H ----
  const int ke = *kep;
#pragma unroll
  for (int j = 0; j < 4; j++) {
    const int lrow = w * 4 + j;
    const long row = m0 + lrow;
    const float4* tsrc = reinterpret_cast<const float4*>(&S->tile[lrow * 1024]);
    float4 q0 = tsrc[lane], q1 = tsrc[64 + lane], q2v = tsrc[128 + lane], q3 = tsrc[192 + lane];
    // stream dots2 (write-only, coalesced)
    float4* ddst = reinterpret_cast<float4*>(d2out + row * 1024);
    ddst[lane] = q0; ddst[64 + lane] = q1; ddst[128 + lane] = q2v; ddst[192 + lane] = q3;

    float x[16] = {q0.x, q0.y, q0.z, q0.w, q1.x, q1.y, q1.z, q1.w,
                   q2v.x, q2v.y, q2v.z, q2v.w, q3.x, q3.y, q3.z, q3.w};
    float mx = x[0];
#pragma unroll
    for (int i = 1; i < 16; i++) mx = fmaxf(mx, x[i]);
    for (int sh = 1; sh < 64; sh <<= 1) mx = fmaxf(mx, __shfl_xor(mx, sh));
    float p[16];
    float se = 0.f;
#pragma unroll
    for (int i = 0; i < 16; i++) { p[i] = __expf(x[i] - mx); se += p[i]; }
    for (int sh = 1; sh < 64; sh <<= 1) se += __shfl_xor(se, sh);
    const float invs = 1.f / se;
    u32 key[16];
#pragma unroll
    for (int i = 0; i < 16; i++) {
      u32 u = __builtin_bit_cast(u32, x[i]);
      key[i] = u ^ ((u >> 31) ? 0xFFFFFFFFu : 0x80000000u);
    }
    u32 lo = 0;
    for (int b = 31; b >= 0; --b) {
      u32 t = lo | (1u << b);
      int cnt = 0;
#pragma unroll
      for (int i = 0; i < 16; i++) cnt += (key[i] >= t);
      for (int sh = 1; sh < 64; sh <<= 1) cnt += __shfl_xor(cnt, sh);
      if (cnt >= ke) lo = t;
    }
    float4 o0, o1, o2, o3;
    o0.x = key[0] >= lo ? p[0] * invs : 0.f;
    o0.y = key[1] >= lo ? p[1] * invs : 0.f;
    o0.z = key[2] >= lo ? p[2] * invs : 0.f;
    o0.w = key[3] >= lo ? p[3] * invs : 0.f;
    o1.x = key[4] >= lo ? p[4] * invs : 0.f;
    o1.y = key[5] >= lo ? p[5] * invs : 0.f;
    o1.z = key[6] >= lo ? p[6] * invs : 0.f;
    o1.w = key[7] >= lo ? p[7] * invs : 0.f;
    o2.x = key[8] >= lo ? p[8] * invs : 0.f;
    o2.y = key[9] >= lo ? p[9] * invs : 0.f;
    o2.z = key[10] >= lo ? p[10] * invs : 0.f;
    o2.w = key[11] >= lo ? p[11] * invs : 0.f;
    o3.x = key[12] >= lo ? p[12] * invs : 0.f;
    o3.y = key[13] >= lo ? p[13] * invs : 0.f;
    o3.z = key[14] >= lo ? p[14] * invs : 0.f;
    o3.w = key[15] >= lo ? p[15] * invs : 0.f;
    float4* dst = reinterpret_cast<float4*>(H + row * 1024);
    dst[lane] = o0;
    dst[64 + lane] = o1;
    dst[128 + lane] = o2;
    dst[192 + lane] = o3;
  }
}

// ---------------------------------------------------------------------------
extern "C" void kernel_launch(void* const* d_in, const int* in_sizes, int n_in,
                              void* d_out, int out_size, void* d_ws, size_t ws_size,
                              hipStream_t stream) {
  (void)in_sizes; (void)n_in; (void)out_size; (void)ws_size;

  float* out = (float*)d_out;
  float* out_edges = out;                       // [1024,256]
  float* out_H = out + NSL * DD;                // [65536,1024]
  float* out_d2 = out_H + NN * NSL;             // [65536,1024]

  // H region scratch (every occupant dead before d3h overwrites with H):
  char* Hb = (char*)out_H;
  u16* dots = (u16*)Hb;                          // 134217728 B
  u16* xln = (u16*)(Hb + 134217728L);            // 32 MB
  u16* kb_ = (u16*)(Hb + 167772160L);            // 32 MB
  u16* vb_ = (u16*)(Hb + 201326592L);            // 32 MB
  char* smb = Hb + 234881024L;
  u16* wcat = (u16*)smb;      smb += 768 * 256 * 2;
  float* bcat = (float*)smb;  smb += 4096;
  float* e_f = (float*)smb;   smb += 1024 * 256 * 4;
  u16* e_b = (u16*)smb;       smb += 1024 * 256 * 2;
  u16* q_b = (u16*)smb;       smb += 1024 * 256 * 2;
  float* updf = (float*)smb;  smb += 1024 * 256 * 4;
  u16* edg_b = (u16*)smb;     smb += 1024 * 256 * 2;
  // dots2 region holds the strided q2 tiles (consumed block-locally by d3h).
  u16* q2s = (u16*)out_d2;
  // k2 in workspace (512 KB): the only scratch that must survive into d3h.
  u16* k2ws = (u16*)d_ws;

  hipFuncSetAttribute(reinterpret_cast<const void*>(d2d3_kernel),
                      hipFuncAttributeMaxDynamicSharedMemorySize,
                      (int)sizeof(D3Shm));
  hipFuncSetAttribute(reinterpret_cast<const void*>(d3h_kernel),
                      hipFuncAttributeMaxDynamicSharedMemorySize,
                      (int)sizeof(D3HShm));

  prep_w_kernel<<<768, 256, 0, stream>>>(
      (const float*)d_in[4], (const float*)d_in[6], (const float*)d_in[8],
      (const float*)d_in[5], (const float*)d_in[7], (const float*)d_in[9], wcat, bcat);
  edges_e_kernel<<<256, 256, 0, stream>>>(
      (const float*)d_in[1], (const float*)d_in[2], (const float*)d_in[3],
      (const float*)d_in[16], (const float*)d_in[17], e_f, e_b);
  ln_x_kernel<<<16384, 256, 0, stream>>>(
      (const float*)d_in[0], (const float*)d_in[14], (const float*)d_in[15], xln);
  gemm_bt<1><<<dim3(2, 8), 256, 0, stream>>>(e_b, wcat + 512 * 256, bcat + 512, 1.f,
                                             q_b, nullptr, nullptr, nullptr);
  gemm_bt<0><<<dim3(6, 512), 256, 0, stream>>>(xln, wcat, bcat, 1.f,
                                               kb_, vb_, q2s, nullptr);
  gemm_bt<2><<<dim3(512, 8), 256, 0, stream>>>(q_b, kb_, nullptr, 0.0625f,
                                               dots, nullptr, nullptr, nullptr);
  d2d3_kernel<<<1024, 1024, sizeof(D3Shm), stream>>>(dots, vb_, (const int*)d_in[18], updf);
  mlp_kernel<<<1024, 256, 0, stream>>>(e_f, updf,
                                       (const float*)d_in[10], (const float*)d_in[11],
                                       (const float*)d_in[12], (const float*)d_in[13],
                                       out_edges, edg_b);
  gemm_bt<1><<<dim3(2, 8), 256, 0, stream>>>(edg_b, wcat, bcat, 1.f,
                                             k2ws, nullptr, nullptr, nullptr);
  d3h_kernel<<<2048, 512, sizeof(D3HShm), stream>>>(q2s, k2ws, (const int*)d_in[19],
                                                    out_d2, out_H);
}

// Round 9
// 651.171 us; speedup vs baseline: 1.5022x; 1.5022x over previous
//
#include <hip/hip_runtime.h>
#include <hip/hip_bf16.h>
#include <stdint.h>

// ---------------------------------------------------------------------------
// HConstructor: slot-attention-like block on MI355X.
//   inputs [65536,256], noise [1024,256] -> edges [1024,256], H [65536,1024],
//   dots2 [65536,1024].
// Pipeline (all on `stream`):
//   prep_w   : Wcat^T = [wk|wv|wq]^T as bf16 [768,256], bias cat
//   edges_e  : edges = mu + exp(ls)*noise ; e = LN(edges)  (f32 + bf16)
//   ln_x     : x = LN(inputs) -> bf16 [65536,256]
//   gemm<1>  : q  = relu(e @ wq + bq)           [1024,256]  bf16
//   gemm<0>  : k,v = relu(x@wk/v + b) -> H-region; q2 strided into dots2 rows
//   gemm<2>  : dots = (q @ k^T) * 1/16 -> bf16 [1024,65536] (H-region scratch)
//   d2d3     : per row: 2-level lane-indexed histogram rank-select + sparse
//              attn@v gather (R6 version, ~161us).
//   mlp      : edges_out = relu([e,upd]@w1+b1)@w2+b2 -> OUT + bf16
//   gemm<1>  : k2 = relu(edges_out @ wk + bk) -> d_ws (512 KB)
//   d3h v3   : FUSED dots2 + H at 2 blocks/CU (80 KB LDS).  R8's 152 KB tile
//              forced 1 block/CU -> 64 barrier-rounds exposed full L2 latency
//              (623us despite ideal traffic).  v3: A(q2) fragments live in
//              REGISTERS (8 v8bf/lane, loaded once); per-row values kept as
//              bf16 KEYS (64 KB) for the top-ke phase; dots2 written exact
//              f32 from accumulators via an 8 KB staging buffer (256 B
//              coalesced segments).  keys 64K + stg 8K + Bk 8K = 80 KB.
// Scratch map:
//   H region   : dots(134M) | xln(32M) | kb(32M) | vb(32M) | smalls(~4M)
//   dots2 reg. : q2-strided tiles (consumed block-locally by d3h)
//   d_ws       : k2 bf16 (512 KB)
// ---------------------------------------------------------------------------

#define DEV __device__ __forceinline__

typedef uint32_t u32;
typedef uint16_t u16;
typedef __bf16 v8bf __attribute__((ext_vector_type(8)));
typedef float v4f __attribute__((ext_vector_type(4)));

static constexpr long NN = 65536;
static constexpr long DD = 256;
static constexpr long NSL = 1024;

DEV u16 f2b(float f) {
  u32 u = __builtin_bit_cast(u32, f);
  u32 r = (u + 0x7FFFu + ((u >> 16) & 1u)) >> 16;
  return (u16)r;
}
DEV float b2f(u16 h) { u32 u = ((u32)h) << 16; return __builtin_bit_cast(float, u); }
// bf16 bits (as u32 low16) -> monotone sortable 16-bit key
DEV u32 b2k(u32 b) { return b ^ (0x8000u + 0x7FFFu * (b >> 15)); }
DEV float k2fv(u32 k) {
  u16 b = (k & 0x8000u) ? (u16)(k ^ 0x8000u) : (u16)(k ^ 0xFFFFu);
  return b2f(b);
}

// ---------------------------------------------------------------------------
// Generic  C[M,N] = epilogue(A[M,256] @ B[N,256]^T)   (bf16 in, MFMA 16x16x32)
// 128x128 tile, BK=64, 4 waves (2x2), XOR-swizzled LDS (16B chunk ^ row&7).
// EPI 0: +biascat, relu for cols<512, route {0:k,1:v,2:q2-strided} bf16
// EPI 1: +bias, relu, bf16 out [M,256]
// EPI 2: *scale, bf16 out ld=65536
// ---------------------------------------------------------------------------
template <int EPI>
__global__ __launch_bounds__(256, 2)
void gemm_bt(const u16* __restrict__ A, const u16* __restrict__ B,
             const float* __restrict__ bias, float scale,
             u16* __restrict__ ob0, u16* __restrict__ ob1, u16* __restrict__ ob2,
             float* __restrict__ of) {
  __shared__ __align__(16) u16 As[128 * 64];
  __shared__ __align__(16) u16 Bs[128 * 64];
  const int tid = threadIdx.x;
  const int lane = tid & 63;
  const int l15 = lane & 15;
  const int l4 = lane >> 4;
  const int wid = tid >> 6;
  const int wm = wid >> 1, wn = wid & 1;
  const long m0 = (long)blockIdx.y * 128;
  const long n0 = (long)blockIdx.x * 128;

  v4f acc[4][4] = {};

  for (int kb = 0; kb < 256; kb += 64) {
    __syncthreads();
#pragma unroll
    for (int i = 0; i < 4; i++) {
      int cid = tid + 256 * i;          // 1024 16B-chunks per tile
      int row = cid >> 3, ch = cid & 7; // 8 chunks per 64-col row
      int sch = ch ^ (row & 7);
      uint4 da = *reinterpret_cast<const uint4*>(A + (m0 + row) * 256 + kb + ch * 8);
      *reinterpret_cast<uint4*>(&As[row * 64 + sch * 8]) = da;
      uint4 db = *reinterpret_cast<const uint4*>(B + (n0 + row) * 256 + kb + ch * 8);
      *reinterpret_cast<uint4*>(&Bs[row * 64 + sch * 8]) = db;
    }
    __syncthreads();
#pragma unroll
    for (int ks = 0; ks < 2; ks++) {
      v8bf af[4], bfr[4];
#pragma unroll
      for (int m = 0; m < 4; m++) {
        int row = wm * 64 + m * 16 + l15;
        int sch = (ks * 4 + l4) ^ (row & 7);
        af[m] = *reinterpret_cast<const v8bf*>(&As[row * 64 + sch * 8]);
      }
#pragma unroll
      for (int n = 0; n < 4; n++) {
        int row = wn * 64 + n * 16 + l15;
        int sch = (ks * 4 + l4) ^ (row & 7);
        bfr[n] = *reinterpret_cast<const v8bf*>(&Bs[row * 64 + sch * 8]);
      }
#pragma unroll
      for (int m = 0; m < 4; m++)
#pragma unroll
        for (int n = 0; n < 4; n++)
          acc[m][n] = __builtin_amdgcn_mfma_f32_16x16x32_bf16(af[m], bfr[n], acc[m][n], 0, 0, 0);
    }
  }

  const int r4 = l4 * 4;
#pragma unroll
  for (int m = 0; m < 4; m++) {
#pragma unroll
    for (int n = 0; n < 4; n++) {
#pragma unroll
      for (int r = 0; r < 4; r++) {
        long grow = m0 + wm * 64 + m * 16 + r4 + r;
        long gcol = n0 + wn * 64 + n * 16 + l15;
        float v = acc[m][n][r];
        if constexpr (EPI == 0) {
          v += bias[gcol];
          int which = (int)(gcol >> 8);
          long jj = gcol & 255;
          if (which < 2) v = fmaxf(v, 0.f);
          u16 hv = f2b(v);
          if (which == 0) ob0[grow * 256 + jj] = hv;
          else if (which == 1) ob1[grow * 256 + jj] = hv;
          else ob2[(grow & ~31L) * 2048 + (grow & 31) * 256 + jj] = hv;  // q2 strided
        } else if constexpr (EPI == 1) {
          v += bias[gcol];
          v = fmaxf(v, 0.f);
          ob0[grow * 256 + gcol] = f2b(v);
        } else if constexpr (EPI == 2) {
          ob0[grow * 65536 + gcol] = f2b(v * scale);
        } else {
          of[grow * 1024 + gcol] = v * scale;
        }
      }
    }
  }
}

// ---------------------------------------------------------------------------
// Weight prep: Wcat^T bf16 [768,256] rows = [wk cols | wv cols | wq cols]
// ---------------------------------------------------------------------------
__global__ __launch_bounds__(256)
void prep_w_kernel(const float* __restrict__ wq, const float* __restrict__ wk,
                   const float* __restrict__ wv, const float* __restrict__ bq,
                   const float* __restrict__ bk, const float* __restrict__ bv,
                   u16* __restrict__ wcat, float* __restrict__ bcat) {
  int n = blockIdx.x;
  int t = threadIdx.x;
  const float* W = (n < 256) ? wk : (n < 512) ? wv : wq;
  int jj = n & 255;
  wcat[n * 256 + t] = f2b(W[t * 256 + jj]);
  if (t == 0) {
    const float* Bb = (n < 256) ? bk : (n < 512) ? bv : bq;
    bcat[n] = Bb[jj];
  }
}

// ---------------------------------------------------------------------------
// x = LayerNorm(inputs) -> bf16.  One wave per row (4 f32 per lane).
// ---------------------------------------------------------------------------
__global__ __launch_bounds__(256)
void ln_x_kernel(const float* __restrict__ x, const float* __restrict__ lw,
                 const float* __restrict__ lb, u16* __restrict__ out) {
  const int lane = threadIdx.x & 63, wid = threadIdx.x >> 6;
  const long row = (long)blockIdx.x * 4 + wid;
  float4 v = reinterpret_cast<const float4*>(x + row * 256)[lane];
  float s = v.x + v.y + v.z + v.w;
  for (int sh = 1; sh < 64; sh <<= 1) s += __shfl_xor(s, sh);
  float mu = s * (1.f / 256.f);
  float dx = v.x - mu, dy = v.y - mu, dz = v.z - mu, dw = v.w - mu;
  float q = dx * dx + dy * dy + dz * dz + dw * dw;
  for (int sh = 1; sh < 64; sh <<= 1) q += __shfl_xor(q, sh);
  float rs = rsqrtf(q * (1.f / 256.f) + 1e-5f);
  float4 wv = reinterpret_cast<const float4*>(lw)[lane];
  float4 bv = reinterpret_cast<const float4*>(lb)[lane];
  ushort4 o4;
  o4.x = f2b(dx * rs * wv.x + bv.x);
  o4.y = f2b(dy * rs * wv.y + bv.y);
  o4.z = f2b(dz * rs * wv.z + bv.z);
  o4.w = f2b(dw * rs * wv.w + bv.w);
  reinterpret_cast<ushort4*>(out + row * 256)[lane] = o4;
}

// ---------------------------------------------------------------------------
// edges = mu + exp(ls)*noise ; e = LayerNorm(edges) -> f32 + bf16
// ---------------------------------------------------------------------------
__global__ __launch_bounds__(256)
void edges_e_kernel(const float* __restrict__ noise, const float* __restrict__ emu,
                    const float* __restrict__ els, const float* __restrict__ lw,
                    const float* __restrict__ lb, float* __restrict__ e_f,
                    u16* __restrict__ e_b) {
  const int lane = threadIdx.x & 63, wid = threadIdx.x >> 6;
  const long row = (long)blockIdx.x * 4 + wid;
  float4 nz = reinterpret_cast<const float4*>(noise + row * 256)[lane];
  float4 mu4 = reinterpret_cast<const float4*>(emu)[lane];
  float4 ls4 = reinterpret_cast<const float4*>(els)[lane];
  float4 ed;
  ed.x = mu4.x + expf(ls4.x) * nz.x;
  ed.y = mu4.y + expf(ls4.y) * nz.y;
  ed.z = mu4.z + expf(ls4.z) * nz.z;
  ed.w = mu4.w + expf(ls4.w) * nz.w;
  float s = ed.x + ed.y + ed.z + ed.w;
  for (int sh = 1; sh < 64; sh <<= 1) s += __shfl_xor(s, sh);
  float mu = s * (1.f / 256.f);
  float dx = ed.x - mu, dy = ed.y - mu, dz = ed.z - mu, dw = ed.w - mu;
  float qv = dx * dx + dy * dy + dz * dz + dw * dw;
  for (int sh = 1; sh < 64; sh <<= 1) qv += __shfl_xor(qv, sh);
  float rs = rsqrtf(qv * (1.f / 256.f) + 1e-5f);
  float4 wv = reinterpret_cast<const float4*>(lw)[lane];
  float4 bv = reinterpret_cast<const float4*>(lb)[lane];
  float4 ef;
  ef.x = dx * rs * wv.x + bv.x;
  ef.y = dy * rs * wv.y + bv.y;
  ef.z = dz * rs * wv.z + bv.z;
  ef.w = dw * rs * wv.w + bv.w;
  reinterpret_cast<float4*>(e_f + row * 256)[lane] = ef;
  ushort4 o4;
  o4.x = f2b(ef.x); o4.y = f2b(ef.y); o4.z = f2b(ef.z); o4.w = f2b(ef.w);
  reinterpret_cast<ushort4*>(e_b + row * 256)[lane] = o4;
}

// ---------------------------------------------------------------------------
// d2d3 (unchanged from R6): 2-level lane-indexed histogram rank select +
// sparse attn@v gather.  Fixed softmax shift C=8 (dots >= 0, O(5)).
// ---------------------------------------------------------------------------
struct D3Shm {
  uint4 SK4[8192];        // 128 KiB packed keys (2 x u16 per u32)
  u32 hist[256 * 16];     // 16 KiB: bin b, copy c at [b*16+c]
  u32 c_hi[256];
  u32 sel_idx[1152];
  float sel_w[1152];
  float fred[16];
  u32 sb_star, sThi, sThr;
  float sSE, sFrac;
  u32 scnt;
};

__global__ __launch_bounds__(1024, 4)
void d2d3_kernel(const u16* __restrict__ dots, const u16* __restrict__ vmat,
                 const int* __restrict__ knp, float* __restrict__ upd) {
  extern __shared__ char d3smem[];
  D3Shm* S = reinterpret_cast<D3Shm*>(d3smem);
  const int tid = threadIdx.x, lane = tid & 63, wid = tid >> 6;
  const int hc = (lane >> 2);          // 16 lane-indexed histogram copies
  const long r = blockIdx.x;
  const int kn = *knp;

  for (int i = tid; i < 4096; i += 1024) S->hist[i] = 0;
  if (tid == 0) S->scnt = 0;
  __syncthreads();

  const float C = 8.f;
  const uint4* src = reinterpret_cast<const uint4*>(dots + r * 65536);

  float se = 0.f;
#pragma unroll
  for (int q = 0; q < 8; q++) {
    uint4 d = src[tid + 1024 * q];
    u32 h[8] = {d.x & 0xffffu, d.x >> 16, d.y & 0xffffu, d.y >> 16,
                d.z & 0xffffu, d.z >> 16, d.w & 0xffffu, d.w >> 16};
    u32 k[8];
#pragma unroll
    for (int j = 0; j < 8; j++) {
      k[j] = b2k(h[j]);
      se += __expf(b2f((u16)h[j]) - C);
      atomicAdd(&S->hist[(k[j] >> 8) * 16 + hc], 1u);
    }
    uint4 kq;
    kq.x = k[0] | (k[1] << 16); kq.y = k[2] | (k[3] << 16);
    kq.z = k[4] | (k[5] << 16); kq.w = k[6] | (k[7] << 16);
    S->SK4[q * 1024 + tid] = kq;
  }
  for (int sh = 1; sh < 64; sh <<= 1) se += __shfl_xor(se, sh);
  if (lane == 0) S->fred[wid] = se;
  __syncthreads();

  if (tid < 256) {
    u32 s = 0;
#pragma unroll
    for (int c = 0; c < 16; c++) s += S->hist[tid * 16 + c];
    S->c_hi[tid] = s;
  }
  __syncthreads();

  if (tid < 64) {
    u32 s = S->c_hi[4 * tid] + S->c_hi[4 * tid + 1] + S->c_hi[4 * tid + 2] + S->c_hi[4 * tid + 3];
    u32 v = s;
    for (int off = 1; off < 64; off <<= 1) {
      u32 t = (u32)__shfl_down((int)v, off);
      if (tid + off < 64) v += t;
    }
    u32 excl = v - s;
    if (v >= (u32)kn && excl < (u32)kn) {
      u32 acc = excl;
#pragma unroll
      for (int bb = 3; bb >= 0; --bb) {
        int b = 4 * tid + bb;
        u32 nb = acc + S->c_hi[b];
        if (nb >= (u32)kn) { S->sb_star = (u32)b; S->sThi = acc; break; }
        acc = nb;
      }
    }
  } else {
    for (int i = tid - 64; i < 4096; i += 960) S->hist[i] = 0;
  }
  __syncthreads();
  const u32 bstar = S->sb_star;

#pragma unroll
  for (int q = 0; q < 8; q++) {
    uint4 kq = S->SK4[q * 1024 + tid];
    u32 w[4] = {kq.x, kq.y, kq.z, kq.w};
#pragma unroll
    for (int j = 0; j < 4; j++) {
      u32 kl = w[j] & 0xffffu, kh = w[j] >> 16;
      if ((kl >> 8) == bstar) atomicAdd(&S->hist[(kl & 255u) * 16 + hc], 1u);
      if ((kh >> 8) == bstar) atomicAdd(&S->hist[(kh & 255u) * 16 + hc], 1u);
    }
  }
  __syncthreads();
  if (tid < 256) {
    u32 s = 0;
#pragma unroll
    for (int c = 0; c < 16; c++) s += S->hist[tid * 16 + c];
    S->c_hi[tid] = s;
  }
  __syncthreads();

  if (tid < 64) {
    u32 s = S->c_hi[4 * tid] + S->c_hi[4 * tid + 1] + S->c_hi[4 * tid + 2] + S->c_hi[4 * tid + 3];
    u32 v = s;
    for (int off = 1; off < 64; off <<= 1) {
      u32 t = (u32)__shfl_down((int)v, off);
      if (tid + off < 64) v += t;
    }
    const u32 Thi = S->sThi;
    u32 incl = v + Thi;
    u32 excl = v - s + Thi;
    if (incl >= (u32)kn && excl < (u32)kn) {
      u32 acc = excl;
#pragma unroll
      for (int bb = 3; bb >= 0; --bb) {
        int b = 4 * tid + bb;
        u32 nb = acc + S->c_hi[b];
        if (nb >= (u32)kn) {
          S->sThr = (bstar << 8) | (u32)b;
          S->sFrac = (float)(int)((u32)kn - acc) / (float)S->c_hi[b];
          break;
        }
        acc = nb;
      }
    }
    if (tid == 0) {
      float SE = 0.f;
#pragma unroll
      for (int i = 0; i < 16; i++) SE += S->fred[i];
      S->sSE = SE;
    }
  }
  __syncthreads();
  const u32 thr = S->sThr;
  const float frac = S->sFrac;
  const float invs = 1.f / S->sSE;
  const float wnorm = 1.f / (1.f + 65536.f * 1e-8f);

#pragma unroll
  for (int q = 0; q < 8; q++) {
    uint4 kq = S->SK4[q * 1024 + tid];
    const u32 base = (u32)(tid + 1024 * q) * 8;
    u32 kk[8] = {kq.x & 0xffffu, kq.x >> 16, kq.y & 0xffffu, kq.y >> 16,
                 kq.z & 0xffffu, kq.z >> 16, kq.w & 0xffffu, kq.w >> 16};
#pragma unroll
    for (int j = 0; j < 8; j++) {
      if (kk[j] >= thr) {
        float w = (__expf(k2fv(kk[j]) - C) * invs + 1e-8f) * wnorm;
        if (kk[j] == thr) w *= frac;
        u32 p = atomicAdd(&S->scnt, 1u);
        if (p < 1152u) { S->sel_idx[p] = base + (u32)j; S->sel_w[p] = w; }
      }
    }
  }
  __syncthreads();
  const u32 nsel = S->scnt < 1152u ? S->scnt : 1152u;

  float* partial = reinterpret_cast<float*>(S->SK4);
  const int g = tid >> 8, col = tid & 255;
  float a0 = 0.f, a1 = 0.f, a2 = 0.f, a3 = 0.f;
  u32 j = (u32)g;
  for (; j + 12 < nsel; j += 16) {
    a0 = fmaf(S->sel_w[j], b2f(vmat[(long)S->sel_idx[j] * 256 + col]), a0);
    a1 = fmaf(S->sel_w[j + 4], b2f(vmat[(long)S->sel_idx[j + 4] * 256 + col]), a1);
    a2 = fmaf(S->sel_w[j + 8], b2f(vmat[(long)S->sel_idx[j + 8] * 256 + col]), a2);
    a3 = fmaf(S->sel_w[j + 12], b2f(vmat[(long)S->sel_idx[j + 12] * 256 + col]), a3);
  }
  for (; j < nsel; j += 4)
    a0 = fmaf(S->sel_w[j], b2f(vmat[(long)S->sel_idx[j] * 256 + col]), a0);
  partial[tid] = (a0 + a1) + (a2 + a3);
  __syncthreads();
  if (tid < 256)
    upd[r * 256 + tid] = partial[tid] + partial[256 + tid] + partial[512 + tid] + partial[768 + tid];
}

// ---------------------------------------------------------------------------
// mlp: edges_out = relu([e, upd] @ w1 + b1) @ w2 + b2   (f32, one block/row)
// ---------------------------------------------------------------------------
__global__ __launch_bounds__(256)
void mlp_kernel(const float* __restrict__ e, const float* __restrict__ upd,
                const float* __restrict__ w1, const float* __restrict__ b1,
                const float* __restrict__ w2, const float* __restrict__ b2,
                float* __restrict__ eout, u16* __restrict__ eb) {
  __shared__ float ecat[512];
  __shared__ float h[256];
  const int t = threadIdx.x;
  const long r = blockIdx.x;
  ecat[t] = e[r * 256 + t];
  ecat[256 + t] = upd[r * 256 + t];
  __syncthreads();
  float acc = b1[t];
#pragma unroll 8
  for (int kk = 0; kk < 512; ++kk) acc = fmaf(ecat[kk], w1[kk * 256 + t], acc);
  h[t] = fmaxf(acc, 0.f);
  __syncthreads();
  float a2 = b2[t];
#pragma unroll 8
  for (int kk = 0; kk < 256; ++kk) a2 = fmaf(h[kk], w2[kk * 256 + t], a2);
  eout[r * 256 + t] = a2;
  eb[r * 256 + t] = f2b(a2);
}

// ---------------------------------------------------------------------------
// d3h v3: FUSED dots2 + H at 2 blocks/CU.  One block = 32 rows, 512 threads,
// 8 waves as 2M(16 rows) x 4N(16 cols each within a 64-col chunk).
//   setup  : A(q2) fragments -> REGISTERS (8 v8bf/lane, one-time L2 read)
//   per nc : 4x { stage Bk[64][64] , 2 MFMA }  -> acc (1 v4f)
//            acc -> stg (f32, 8 KB) + keys (bf16)
//            barrier; coalesced 256 B-segment float4 writes of dots2
//   final  : per-wave top-ke over 4 rows from bf16 keys (16-step search on
//            monotone 16-bit keys); H written as contiguous 64 B/lane.
// LDS = keys 64K + stg 8K + Bk 8K = 80 KB -> 2 blocks/CU (fixes R8's
// 1-block/CU barrier serialization).
// ---------------------------------------------------------------------------
struct D3HShm {
  u16 keys[32 * 1024];     // 64 KiB bf16 dots2 values
  float stg[32 * 64];      // 8 KiB f32 write-staging (one 64-col stripe)
  u16 Bk[64 * 64];         // 8 KiB
};

__global__ __launch_bounds__(512, 4)
void d3h_kernel(const u16* __restrict__ q2s, const u16* __restrict__ k2,
                const int* __restrict__ kep, float* __restrict__ d2out,
                float* __restrict__ H) {
  extern __shared__ char d3hsm[];
  D3HShm* S = reinterpret_cast<D3HShm*>(d3hsm);
  const int tid = threadIdx.x;
  const int lane = tid & 63;
  const int l15 = lane & 15;
  const int l4 = lane >> 4;
  const int w = tid >> 6;
  const int wm = w >> 2, wn = w & 3;
  const long m0 = (long)blockIdx.x * 32;

  // ---- A fragments into registers (one-time; q2 tile is 16 KB, L2-hot) ----
  const u16* q2blk = q2s + m0 * 2048;          // own strided slot
  const int arow = wm * 16 + l15;
  v8bf afrag[8];
#pragma unroll
  for (int kb = 0; kb < 4; kb++)
#pragma unroll
    for (int ks = 0; ks < 2; ks++)
      afrag[kb * 2 + ks] = *reinterpret_cast<const v8bf*>(
          q2blk + arow * 256 + kb * 64 + ks * 32 + l4 * 8);

  const int brow = wn * 16 + l15;

  // ---- 16 col-chunks of 64 ----
#pragma unroll 1
  for (int nc = 0; nc < 16; nc++) {
    v4f acc = {};
#pragma unroll
    for (int kb = 0; kb < 4; kb++) {
      __syncthreads();                         // also guards stg reuse
      {
        int row = tid >> 3, ch = tid & 7;      // 512 x 16B chunks
        int sch = ch ^ (row & 7);
        uint4 d = *reinterpret_cast<const uint4*>(k2 + (nc * 64 + row) * 256 + kb * 64 + ch * 8);
        *reinterpret_cast<uint4*>(&S->Bk[row * 64 + sch * 8]) = d;
      }
      __syncthreads();
#pragma unroll
      for (int ks = 0; ks < 2; ks++) {
        v8bf b = *reinterpret_cast<const v8bf*>(
            &S->Bk[brow * 64 + (((ks * 4 + l4) ^ (brow & 7))) * 8]);
        acc = __builtin_amdgcn_mfma_f32_16x16x32_bf16(afrag[kb * 2 + ks], b, acc, 0, 0, 0);
      }
    }
    // scale; stash f32 into stg and bf16 into keys
#pragma unroll
    for (int r = 0; r < 4; r++) {
      int lr = wm * 16 + l4 * 4 + r;           // 0..31
      int lc = wn * 16 + l15;                  // 0..63
      float v = acc[r] * 0.0625f;
      S->stg[lr * 64 + lc] = v;
      S->keys[lr * 1024 + nc * 64 + lc] = f2b(v);
    }
    __syncthreads();
    // coalesced dots2 write of this 64-col stripe (256 B segments)
    {
      int row = tid >> 4;                      // 0..31
      int c4 = (tid & 15) * 4;                 // 0..60
      float4 v = *reinterpret_cast<const float4*>(&S->stg[row * 64 + c4]);
      *reinterpret_cast<float4*>(&d2out[(m0 + row) * 1024 + nc * 64 + c4]) = v;
    }
  }
  __syncthreads();

  // ---- top-ke phase: wave w owns rows m0 + w*4 .. +3, from bf16 keys ----
  const int ke = *kep;
#pragma unroll
  for (int j = 0; j < 4; j++) {
    const int lrow = w * 4 + j;
    const long row = m0 + lrow;
    uint4 ka = *reinterpret_cast<const uint4*>(&S->keys[lrow * 1024 + lane * 16]);
    uint4 kb2 = *reinterpret_cast<const uint4*>(&S->keys[lrow * 1024 + lane * 16 + 8]);
    u32 kw[8] = {ka.x, ka.y, ka.z, ka.w, kb2.x, kb2.y, kb2.z, kb2.w};
    u32 k16[16];
    float x[16];
#pragma unroll
    for (int i = 0; i < 8; i++) {
      u32 lo16 = kw[i] & 0xffffu, hi16 = kw[i] >> 16;
      k16[2 * i] = b2k(lo16);     x[2 * i] = b2f((u16)lo16);
      k16[2 * i + 1] = b2k(hi16); x[2 * i + 1] = b2f((u16)hi16);
    }
    float mx = x[0];
#pragma unroll
    for (int i = 1; i < 16; i++) mx = fmaxf(mx, x[i]);
    for (int sh = 1; sh < 64; sh <<= 1) mx = fmaxf(mx, __shfl_xor(mx, sh));
    float p[16];
    float se = 0.f;
#pragma unroll
    for (int i = 0; i < 16; i++) { p[i] = __expf(x[i] - mx); se += p[i]; }
    for (int sh = 1; sh < 64; sh <<= 1) se += __shfl_xor(se, sh);
    const float invs = 1.f / se;
    u32 lo = 0;
    for (int b = 15; b >= 0; --b) {
      u32 t = lo | (1u << b);
      int cnt = 0;
#pragma unroll
      for (int i = 0; i < 16; i++) cnt += (k16[i] >= t);
      for (int sh = 1; sh < 64; sh <<= 1) cnt += __shfl_xor(cnt, sh);
      if (cnt >= ke) lo = t;
    }
    float o[16];
#pragma unroll
    for (int i = 0; i < 16; i++) o[i] = (k16[i] >= lo) ? p[i] * invs : 0.f;
    float4* dst = reinterpret_cast<float4*>(&H[row * 1024 + lane * 16]);
#pragma unroll
    for (int i = 0; i < 4; i++) {
      float4 ov;
      ov.x = o[4 * i]; ov.y = o[4 * i + 1]; ov.z = o[4 * i + 2]; ov.w = o[4 * i + 3];
      dst[i] = ov;
    }
  }
}

// ---------------------------------------------------------------------------
extern "C" void kernel_launch(void* const* d_in, const int* in_sizes, int n_in,
                              void* d_out, int out_size, void* d_ws, size_t ws_size,
                              hipStream_t stream) {
  (void)in_sizes; (void)n_in; (void)out_size; (void)ws_size;

  float* out = (float*)d_out;
  float* out_edges = out;                       // [1024,256]
  float* out_H = out + NSL * DD;                // [65536,1024]
  float* out_d2 = out_H + NN * NSL;             // [65536,1024]

  // H region scratch (every occupant dead before d3h overwrites with H):
  char* Hb = (char*)out_H;
  u16* dots = (u16*)Hb;                          // 134217728 B
  u16* xln = (u16*)(Hb + 134217728L);            // 32 MB
  u16* kb_ = (u16*)(Hb + 167772160L);            // 32 MB
  u16* vb_ = (u16*)(Hb + 201326592L);            // 32 MB
  char* smb = Hb + 234881024L;
  u16* wcat = (u16*)smb;      smb += 768 * 256 * 2;
  float* bcat = (float*)smb;  smb += 4096;
  float* e_f = (float*)smb;   smb += 1024 * 256 * 4;
  u16* e_b = (u16*)smb;       smb += 1024 * 256 * 2;
  u16* q_b = (u16*)smb;       smb += 1024 * 256 * 2;
  float* updf = (float*)smb;  smb += 1024 * 256 * 4;
  u16* edg_b = (u16*)smb;     smb += 1024 * 256 * 2;
  // dots2 region holds the strided q2 tiles (consumed block-locally by d3h).
  u16* q2s = (u16*)out_d2;
  // k2 in workspace (512 KB): the only scratch that must survive into d3h.
  u16* k2ws = (u16*)d_ws;

  hipFuncSetAttribute(reinterpret_cast<const void*>(d2d3_kernel),
                      hipFuncAttributeMaxDynamicSharedMemorySize,
                      (int)sizeof(D3Shm));
  hipFuncSetAttribute(reinterpret_cast<const void*>(d3h_kernel),
                      hipFuncAttributeMaxDynamicSharedMemorySize,
                      (int)sizeof(D3HShm));

  prep_w_kernel<<<768, 256, 0, stream>>>(
      (const float*)d_in[4], (const float*)d_in[6], (const float*)d_in[8],
      (const float*)d_in[5], (const float*)d_in[7], (const float*)d_in[9], wcat, bcat);
  edges_e_kernel<<<256, 256, 0, stream>>>(
      (const float*)d_in[1], (const float*)d_in[2], (const float*)d_in[3],
      (const float*)d_in[16], (const float*)d_in[17], e_f, e_b);
  ln_x_kernel<<<16384, 256, 0, stream>>>(
      (const float*)d_in[0], (const float*)d_in[14], (const float*)d_in[15], xln);
  gemm_bt<1><<<dim3(2, 8), 256, 0, stream>>>(e_b, wcat + 512 * 256, bcat + 512, 1.f,
                                             q_b, nullptr, nullptr, nullptr);
  gemm_bt<0><<<dim3(6, 512), 256, 0, stream>>>(xln, wcat, bcat, 1.f,
                                               kb_, vb_, q2s, nullptr);
  gemm_bt<2><<<dim3(512, 8), 256, 0, stream>>>(q_b, kb_, nullptr, 0.0625f,
                                               dots, nullptr, nullptr, nullptr);
  d2d3_kernel<<<1024, 1024, sizeof(D3Shm), stream>>>(dots, vb_, (const int*)d_in[18], updf);
  mlp_kernel<<<1024, 256, 0, stream>>>(e_f, updf,
                                       (const float*)d_in[10], (const float*)d_in[11],
                                       (const float*)d_in[12], (const float*)d_in[13],
                                       out_edges, edg_b);
  gemm_bt<1><<<dim3(2, 8), 256, 0, stream>>>(edg_b, wcat, bcat, 1.f,
                                             k2ws, nullptr, nullptr, nullptr);
  d3h_kernel<<<2048, 512, sizeof(D3HShm), stream>>>(q2s, k2ws, (const int*)d_in[19],
                                                    out_d2, out_H);
}